// Round 4
// baseline (888.410 us; speedup 1.0000x reference)
//
#include <hip/hip_runtime.h>
#include <math.h>

typedef short s16x8 __attribute__((ext_vector_type(8)));
typedef float f32x4 __attribute__((ext_vector_type(4)));

#define SLOPE 0.2f
#define K1 1433
#define KP 1440   // K padded to multiple of 32
#define NKB 45    // KP/32

static __device__ __forceinline__ float leaky(float x) {
  return x > 0.f ? x : SLOPE * x;
}

static __device__ __forceinline__ unsigned short f2bf(float f) {
  unsigned u = __builtin_bit_cast(unsigned, f);
  u += 0x7FFFu + ((u >> 16) & 1u);
  return (unsigned short)(u >> 16);
}
static __device__ __forceinline__ float bf2f(unsigned short h) {
  unsigned u = ((unsigned)h) << 16;
  return __builtin_bit_cast(float, u);
}

// --------- W1 -> fragment-order hi/lo bf16 table ---------
// layout: [(kb*2 + hl)*16 + ntg][lane 0..63][8 ushorts]
// value = W1[k][n], n = ntg*16 + (l&15), k = kb*32 + (l>>4)*8 + e (0 pad k>=K1)
__global__ void w1t_kernel(const float* __restrict__ W1,
                           unsigned short* __restrict__ w1f) {
  int tid = blockIdx.x * 256 + threadIdx.x;       // one thread = one 16B chunk
  if (tid >= NKB * 2 * 16 * 64) return;
  int l = tid & 63;
  int chunk = tid >> 6;                            // (kb*2+hl)*16 + ntg
  int ntg = chunk & 15;
  int hl = (chunk >> 4) & 1;
  int kb = chunk >> 5;
  int n = ntg * 16 + (l & 15);
  int kbase = kb * 32 + (l >> 4) * 8;
  unsigned short o[8];
#pragma unroll
  for (int e = 0; e < 8; ++e) {
    int k = kbase + e;
    float v = (k < K1) ? W1[(long)k * 256 + n] : 0.f;
    unsigned short h = f2bf(v);
    o[e] = hl ? f2bf(v - bf2f(h)) : h;
  }
  *(ulonglong2*)(w1f + (long)tid * 8) = *(ulonglong2*)o;
}

// --------- GEMM1 via split-bf16 MFMA, fragment-order LDS ---------
// block: 256 thr = 4 waves (2x2 of 64x64 wave tiles). BM=128, BN=128, BK=32.
// As/Bs layout: [tile][hl][lane][8 ushorts]  (lane-linear => conflict-free reads)
__global__ __launch_bounds__(256) void gemm1_mfma_kernel(
    const float* __restrict__ A, const unsigned short* __restrict__ w1f,
    float* __restrict__ C, int M) {
  __shared__ unsigned short As[8 * 2 * 64 * 8];   // 16 KB
  __shared__ unsigned short Bs[8 * 2 * 64 * 8];   // 16 KB
  const int t = threadIdx.x;
  const int w = t >> 6, l = t & 63;
  const int wm = w >> 1, wn = w & 1;
  const int row0 = blockIdx.x * 128;
  const int nblk = blockIdx.y;                     // 0/1 -> cols 0-127 / 128-255

  f32x4 acc[4][4];
#pragma unroll
  for (int mt = 0; mt < 4; ++mt)
#pragma unroll
    for (int nt = 0; nt < 4; ++nt)
#pragma unroll
      for (int r = 0; r < 4; ++r) acc[mt][nt][r] = 0.f;

  const int sr = t >> 1;            // A stage row 0..127
  const int sk = (t & 1) * 16;      // k offset 0 / 16
  const int smt = sr >> 4;          // A tile
  const int slr = sr & 15;          // lane row-part

  for (int kb = 0; kb < NKB; ++kb) {
    const int k0 = kb * 32;
    // ---- stage B: 4 global_load_lds (16B) per wave, lane-linear dest
#pragma unroll
    for (int q = 0; q < 4; ++q) {
      int c = w * 4 + q;            // chunk 0..15: nt = c>>1, hl = c&1
      int nt = c >> 1, hl = c & 1;
      const unsigned short* gsrc =
          w1f + ((((long)kb * 2 + hl) * 16 + nblk * 8 + nt) * 64 + l) * 8;
      unsigned short* ldst = &Bs[(nt * 2 + hl) * 512];
      __builtin_amdgcn_global_load_lds(
          (const __attribute__((address_space(1))) unsigned int*)gsrc,
          (__attribute__((address_space(3))) unsigned int*)ldst, 16, 0, 0);
    }
    // ---- stage A: 16 floats -> hi/lo, 4 lane-chunk writes
    {
      int grow = row0 + sr;
      float v[16];
      if (grow < M) {
        const float* ap = A + (long)grow * K1;
#pragma unroll
        for (int i = 0; i < 16; ++i) {
          int gk = k0 + sk + i;
          v[i] = (gk < K1) ? ap[gk] : 0.f;
        }
      } else {
#pragma unroll
        for (int i = 0; i < 16; ++i) v[i] = 0.f;
      }
#pragma unroll
      for (int g = 0; g < 2; ++g) {                // two 8-k groups
        unsigned short hv[8], lv[8];
#pragma unroll
        for (int e = 0; e < 8; ++e) {
          float f = v[g * 8 + e];
          unsigned short h = f2bf(f);
          hv[e] = h;
          lv[e] = f2bf(f - bf2f(h));
        }
        int lane_dst = slr + 16 * (sk / 8 + g);
        *(ulonglong2*)&As[((smt * 2 + 0) * 64 + lane_dst) * 8] = *(ulonglong2*)hv;
        *(ulonglong2*)&As[((smt * 2 + 1) * 64 + lane_dst) * 8] = *(ulonglong2*)lv;
      }
    }
    __syncthreads();
    // ---- fragments (lane-linear reads) + 48 MFMA
    {
      s16x8 bh[4], bl[4];
#pragma unroll
      for (int nt = 0; nt < 4; ++nt) {
        int ng = wn * 4 + nt;
        bh[nt] = *(const s16x8*)&Bs[(ng * 2 + 0) * 512 + l * 8];
        bl[nt] = *(const s16x8*)&Bs[(ng * 2 + 1) * 512 + l * 8];
      }
#pragma unroll
      for (int mt = 0; mt < 4; ++mt) {
        int mg = wm * 4 + mt;
        s16x8 ah = *(const s16x8*)&As[(mg * 2 + 0) * 512 + l * 8];
        s16x8 al = *(const s16x8*)&As[(mg * 2 + 1) * 512 + l * 8];
#pragma unroll
        for (int nt = 0; nt < 4; ++nt) {
          acc[mt][nt] = __builtin_amdgcn_mfma_f32_16x16x32_bf16(
              ah, bh[nt], acc[mt][nt], 0, 0, 0);
          acc[mt][nt] = __builtin_amdgcn_mfma_f32_16x16x32_bf16(
              ah, bl[nt], acc[mt][nt], 0, 0, 0);
          acc[mt][nt] = __builtin_amdgcn_mfma_f32_16x16x32_bf16(
              al, bh[nt], acc[mt][nt], 0, 0, 0);
        }
      }
    }
    __syncthreads();
  }
  // ---- epilogue: tile D layout col = l&15, row = (l>>4)*4 + r
  const int crow4 = (l >> 4) * 4;
  const int ccol = l & 15;
#pragma unroll
  for (int mt = 0; mt < 4; ++mt) {
#pragma unroll
    for (int r = 0; r < 4; ++r) {
      int grow = row0 + wm * 64 + mt * 16 + crow4 + r;
      if (grow < M) {
#pragma unroll
        for (int nt = 0; nt < 4; ++nt) {
          int gcol = nblk * 128 + wn * 64 + nt * 16 + ccol;
          C[(long)grow * 256 + gcol] = acc[mt][nt][r];
        }
      }
    }
  }
}

// ---------------- per-node attention logits, layer 1 ----------------
__global__ void alpha1_kernel(const float* __restrict__ h1,
    const float* __restrict__ a_src, const float* __restrict__ a_dst,
    float* __restrict__ as_o, float* __restrict__ ad_o, int N) {
  int i = blockIdx.x * blockDim.x + threadIdx.x;  // i = n*8+h
  if (i >= N * 8) return;
  int h = i & 7;
  const float* hp = h1 + (long)(i >> 3) * 256 + h * 32;
  const float* sp = a_src + h * 32;
  const float* dp = a_dst + h * 32;
  float s1 = 0.f, s2 = 0.f;
#pragma unroll
  for (int c = 0; c < 32; c += 4) {
    float4 v = *(const float4*)(hp + c);
    float4 ws = *(const float4*)(sp + c);
    float4 wd = *(const float4*)(dp + c);
    s1 += v.x * ws.x + v.y * ws.y + v.z * ws.z + v.w * ws.w;
    s2 += v.x * wd.x + v.y * wd.y + v.z * wd.z + v.w * wd.w;
  }
  as_o[i] = s1;
  ad_o[i] = s2;
}

// ================= CSR construction =================
__global__ void hist_kernel(const int* __restrict__ dst, int* __restrict__ cnt,
                            int E, int N) {
  int e = blockIdx.x * blockDim.x + threadIdx.x;
  if (e >= E + N) return;
  int d = (e < E) ? dst[e] : (e - E);
  atomicAdd(&cnt[d], 1);
}

__global__ __launch_bounds__(1024) void scan_kernel(
    const int* __restrict__ cnt, int* __restrict__ rowptr,
    int* __restrict__ cursor, int N) {
  __shared__ int part[1024];
  const int tid = threadIdx.x;
  const int chunk = (N + 1023) / 1024;
  const int base = tid * chunk;
  const int lim = min(base + chunk, N);
  int sum = 0;
  for (int i = base; i < lim; ++i) sum += cnt[i];
  part[tid] = sum;
  __syncthreads();
  for (int off = 1; off < 1024; off <<= 1) {
    int v = (tid >= off) ? part[tid - off] : 0;
    __syncthreads();
    part[tid] += v;
    __syncthreads();
  }
  int run = (tid == 0) ? 0 : part[tid - 1];
  for (int i = base; i < lim; ++i) {
    rowptr[i] = run;
    cursor[i] = run;
    run += cnt[i];
  }
  if (tid == 1023) rowptr[N] = part[1023];
}

__global__ void scatter_kernel(const int* __restrict__ src,
    const int* __restrict__ dst, int* __restrict__ cursor,
    int* __restrict__ csr_src, int E, int N) {
  int e = blockIdx.x * blockDim.x + threadIdx.x;
  if (e >= E + N) return;
  int s, d;
  if (e < E) { s = src[e]; d = dst[e]; } else { s = e - E; d = s; }
  int pos = atomicAdd(&cursor[d], 1);
  csr_src[pos] = s;
}

// ======== layer-1 fused aggregation: wave per dst, no atomics ========
__global__ __launch_bounds__(256) void agg1_fused_kernel(
    const int* __restrict__ rowptr, const int* __restrict__ csr_src,
    const float* __restrict__ as_, const float* __restrict__ ad_,
    const float* __restrict__ h1, const float* __restrict__ bias,
    float* __restrict__ act, int N) {
  int d = blockIdx.x * 4 + (threadIdx.x >> 6);
  if (d >= N) return;
  int l = threadIdx.x & 63;
  int h = l >> 3;
  int rs = rowptr[d], re = rowptr[d + 1];
  float adv = ad_[d * 8 + h];
  float4 acc = make_float4(0.f, 0.f, 0.f, 0.f);
  float den = 0.f;
  for (int i = rs; i < re; ++i) {
    int s = csr_src[i];
    float a = __expf(leaky(as_[s * 8 + h] + adv));
    den += a;
    float4 v = *(const float4*)(h1 + (long)s * 256 + l * 4);
    acc.x += a * v.x; acc.y += a * v.y; acc.z += a * v.z; acc.w += a * v.w;
  }
  float inv = 1.f / den;
  float4 b = *(const float4*)(bias + l * 4);
  float4 o;
  o.x = acc.x * inv + b.x; o.y = acc.y * inv + b.y;
  o.z = acc.z * inv + b.z; o.w = acc.w * inv + b.w;
  o.x = o.x > 0.f ? o.x : expm1f(o.x);
  o.y = o.y > 0.f ? o.y : expm1f(o.y);
  o.z = o.z > 0.f ? o.z : expm1f(o.z);
  o.w = o.w > 0.f ? o.w : expm1f(o.w);
  *(float4*)(act + (long)d * 256 + l * 4) = o;
}

// ---------------- GEMM2 (K=256, N=56) + fused alpha2 ----------------
__global__ __launch_bounds__(256) void gemm2_kernel(const float* __restrict__ act,
    const float* __restrict__ W2, const float* __restrict__ a_src2,
    const float* __restrict__ a_dst2, float* __restrict__ h2,
    float* __restrict__ as_o, float* __restrict__ ad_o, int N) {
  __shared__ float Ws[256 * 56];
  for (int i = threadIdx.x; i < 256 * 56; i += 256) Ws[i] = W2[i];
  __syncthreads();
  int n = blockIdx.x * 32 + (threadIdx.x >> 3);
  int h = threadIdx.x & 7;
  if (n >= N) return;
  const float* ap = act + (long)n * 256;
  float acc[7] = {0.f, 0.f, 0.f, 0.f, 0.f, 0.f, 0.f};
  for (int k0 = 0; k0 < 256; k0 += 4) {
    float4 a = *(const float4*)(ap + k0);
    float av[4] = {a.x, a.y, a.z, a.w};
#pragma unroll
    for (int kk = 0; kk < 4; ++kk) {
      const float* wp = &Ws[(k0 + kk) * 56 + h * 7];
#pragma unroll
      for (int j = 0; j < 7; ++j) acc[j] += av[kk] * wp[j];
    }
  }
  float* hp = h2 + (long)n * 56 + h * 7;
  float s1 = 0.f, s2 = 0.f;
#pragma unroll
  for (int j = 0; j < 7; ++j) {
    hp[j] = acc[j];
    s1 += acc[j] * a_src2[h * 7 + j];
    s2 += acc[j] * a_dst2[h * 7 + j];
  }
  as_o[n * 8 + h] = s1;
  ad_o[n * 8 + h] = s2;
}

// ======== layer-2 fused aggregation: wave per dst ========
__global__ __launch_bounds__(256) void agg2_fused_kernel(
    const int* __restrict__ rowptr, const int* __restrict__ csr_src,
    const float* __restrict__ as_, const float* __restrict__ ad_,
    const float* __restrict__ h2, const float* __restrict__ bias,
    float* __restrict__ out, int N) {
  int d = blockIdx.x * 4 + (threadIdx.x >> 6);
  if (d >= N) return;
  int l = threadIdx.x & 63;
  int h = l >> 3, j = l & 7;
  int rs = rowptr[d], re = rowptr[d + 1];
  float adv = ad_[d * 8 + h];
  float acc = 0.f, den = 0.f;
  for (int i = rs; i < re; ++i) {
    int s = csr_src[i];
    float a = __expf(leaky(as_[s * 8 + h] + adv));
    den += a;
    if (j < 7) acc += a * h2[(long)s * 56 + h * 7 + j];
  }
  if (j < 7) out[(long)d * 56 + h * 7 + j] = acc / den + bias[h * 7 + j];
}

extern "C" void kernel_launch(void* const* d_in, const int* in_sizes, int n_in,
                              void* d_out, int out_size, void* d_ws, size_t ws_size,
                              hipStream_t stream) {
  const float* x    = (const float*)d_in[0];
  const int*   ei   = (const int*)d_in[1];
  const float* W1   = (const float*)d_in[2];
  const float* asr1 = (const float*)d_in[3];
  const float* adt1 = (const float*)d_in[4];
  const float* b1   = (const float*)d_in[5];
  const float* W2   = (const float*)d_in[6];
  const float* asr2 = (const float*)d_in[7];
  const float* adt2 = (const float*)d_in[8];
  const float* b2   = (const float*)d_in[9];
  float* out = (float*)d_out;

  const int N = in_sizes[0] / K1;
  const int E = in_sizes[1] / 2;
  const int* src = ei;
  const int* dst = ei + E;

  float* ws = (float*)d_ws;
  float* h1  = ws; ws += (long)N * 256;
  float* act = ws; ws += (long)N * 256;
  float* h2  = ws; ws += (long)N * 56;
  float* as1 = ws; ws += N * 8;
  float* ad1 = ws; ws += N * 8;
  float* as2 = ws; ws += N * 8;
  float* ad2 = ws; ws += N * 8;
  unsigned short* w1f = (unsigned short*)ws; ws += NKB * 2 * 16 * 64 * 8 / 2;
  int* cnt     = (int*)ws; ws += N;
  int* rowptr  = (int*)ws; ws += N + 1;
  int* cursor  = (int*)ws; ws += N;
  int* csr_src = (int*)ws; ws += E + N;

  hipMemsetAsync(cnt, 0, (size_t)N * sizeof(int), stream);

  dim3 blk(256);

  // CSR build + weight re-layout (cheap)
  hist_kernel<<<dim3((E + N + 255) / 256), blk, 0, stream>>>(dst, cnt, E, N);
  scan_kernel<<<dim3(1), dim3(1024), 0, stream>>>(cnt, rowptr, cursor, N);
  scatter_kernel<<<dim3((E + N + 255) / 256), blk, 0, stream>>>(
      src, dst, cursor, csr_src, E, N);
  {
    int tot = NKB * 2 * 16 * 64;
    w1t_kernel<<<dim3((tot + 255) / 256), blk, 0, stream>>>(W1, w1f);
  }

  gemm1_mfma_kernel<<<dim3((N + 127) / 128, 2), blk, 0, stream>>>(x, w1f, h1, N);
  alpha1_kernel<<<dim3((N * 8 + 255) / 256), blk, 0, stream>>>(h1, asr1, adt1, as1, ad1, N);
  agg1_fused_kernel<<<dim3((N + 3) / 4), blk, 0, stream>>>(
      rowptr, csr_src, as1, ad1, h1, b1, act, N);
  gemm2_kernel<<<dim3((N + 31) / 32), blk, 0, stream>>>(act, W2, asr2, adt2, h2, as2, ad2, N);
  agg2_fused_kernel<<<dim3((N + 3) / 4), blk, 0, stream>>>(
      rowptr, csr_src, as2, ad2, h2, b2, out, N);
}

// Round 6
// 742.635 us; speedup vs baseline: 1.1963x; 1.1963x over previous
//
#include <hip/hip_runtime.h>
#include <math.h>

typedef short s16x8 __attribute__((ext_vector_type(8)));
typedef float f32x4 __attribute__((ext_vector_type(4)));

#define SLOPE 0.2f
#define K1 1433
#define KP 1440   // K padded to multiple of 32
#define NKB 45    // KP/32

static __device__ __forceinline__ float leaky(float x) {
  return x > 0.f ? x : SLOPE * x;
}

static __device__ __forceinline__ unsigned short f2bf(float f) {
  unsigned u = __builtin_bit_cast(unsigned, f);
  u += 0x7FFFu + ((u >> 16) & 1u);
  return (unsigned short)(u >> 16);
}
static __device__ __forceinline__ float bf2f(unsigned short h) {
  unsigned u = ((unsigned)h) << 16;
  return __builtin_bit_cast(float, u);
}

// --------- W1 -> fragment-order hi/lo bf16 table ---------
// layout: [(kb*2 + hl)*16 + ntg][lane 0..63][8 ushorts]
// value = W1[k][n], n = ntg*16 + (l&15), k = kb*32 + (l>>4)*8 + e (0 pad k>=K1)
__global__ void w1t_kernel(const float* __restrict__ W1,
                           unsigned short* __restrict__ w1f) {
  int tid = blockIdx.x * 256 + threadIdx.x;       // one thread = one 16B chunk
  if (tid >= NKB * 2 * 16 * 64) return;
  int l = tid & 63;
  int chunk = tid >> 6;                            // (kb*2+hl)*16 + ntg
  int ntg = chunk & 15;
  int hl = (chunk >> 4) & 1;
  int kb = chunk >> 5;
  int n = ntg * 16 + (l & 15);
  int kbase = kb * 32 + (l >> 4) * 8;
  unsigned short o[8];
#pragma unroll
  for (int e = 0; e < 8; ++e) {
    int k = kbase + e;
    float v = (k < K1) ? W1[(long)k * 256 + n] : 0.f;
    unsigned short h = f2bf(v);
    o[e] = hl ? f2bf(v - bf2f(h)) : h;
  }
  *(ulonglong2*)(w1f + (long)tid * 8) = *(ulonglong2*)o;
}

// --------- GEMM1 via split-bf16 MFMA, pipelined, fragment-order LDS ---------
// block: 256 thr = 4 waves, each owning a 64x64 wave tile (BM=64, BN=256, BK=32).
// A read exactly once. Double-buffered As (2x8KB) + Bs (2x32KB) = 80KB -> 2 blk/CU.
// One __syncthreads per K-step; B(t+1)/A(t+1) issued before MFMA(t).
__global__ __launch_bounds__(256) void gemm1_mfma_kernel(
    const float* __restrict__ A, const unsigned short* __restrict__ w1f,
    float* __restrict__ C, int M) {
  __shared__ unsigned short As[2][4 * 2 * 64 * 8];    // 2 x 8 KB
  __shared__ unsigned short Bs[2][16 * 2 * 64 * 8];   // 2 x 32 KB
  const int t = threadIdx.x;
  const int w = t >> 6, l = t & 63;
  const int row0 = blockIdx.x * 64;

  f32x4 acc[4][4];
#pragma unroll
  for (int mt = 0; mt < 4; ++mt)
#pragma unroll
    for (int nt = 0; nt < 4; ++nt)
#pragma unroll
      for (int r = 0; r < 4; ++r) acc[mt][nt][r] = 0.f;

  // A staging geometry: row sr = t>>2 (0..63), k-group sg = t&3 (8 k each)
  const int sr = t >> 2, sg = t & 3;
  const int smt = sr >> 4, slr = sr & 15;
  const int lane_dst = slr + 16 * sg;           // fragment lane index
  const bool rowok = (row0 + sr) < M;
  const float* arow = A + (long)(row0 + sr) * K1;

  float v[8];

  // prologue: stage tile 0
#pragma unroll
  for (int q = 0; q < 8; ++q) {
    int c = w * 8 + q, ng = c >> 1, hl = c & 1;
    const unsigned short* gsrc = w1f + ((((long)0 * 2 + hl) * 16 + ng) * 64 + l) * 8;
    unsigned short* ldst = &Bs[0][(ng * 2 + hl) * 512];
    __builtin_amdgcn_global_load_lds(
        (const __attribute__((address_space(1))) unsigned int*)gsrc,
        (__attribute__((address_space(3))) unsigned int*)ldst, 16, 0, 0);
  }
  {
    int kbase = sg * 8;
#pragma unroll
    for (int i = 0; i < 8; ++i) {
      int gk = kbase + i;
      v[i] = (rowok && gk < K1) ? arow[gk] : 0.f;
    }
    unsigned short hv[8], lv[8];
#pragma unroll
    for (int e = 0; e < 8; ++e) {
      unsigned short h = f2bf(v[e]);
      hv[e] = h;
      lv[e] = f2bf(v[e] - bf2f(h));
    }
    *(ulonglong2*)&As[0][((smt * 2 + 0) * 64 + lane_dst) * 8] = *(ulonglong2*)hv;
    *(ulonglong2*)&As[0][((smt * 2 + 1) * 64 + lane_dst) * 8] = *(ulonglong2*)lv;
  }
  __syncthreads();

  int cur = 0;
  for (int kb = 0; kb < NKB; ++kb) {
    const int nxt = kb + 1;
    // ---- issue next tile's loads (latency hides under MFMA below)
    if (nxt < NKB) {
#pragma unroll
      for (int q = 0; q < 8; ++q) {
        int c = w * 8 + q, ng = c >> 1, hl = c & 1;
        const unsigned short* gsrc =
            w1f + ((((long)nxt * 2 + hl) * 16 + ng) * 64 + l) * 8;
        unsigned short* ldst = &Bs[cur ^ 1][(ng * 2 + hl) * 512];
        __builtin_amdgcn_global_load_lds(
            (const __attribute__((address_space(1))) unsigned int*)gsrc,
            (__attribute__((address_space(3))) unsigned int*)ldst, 16, 0, 0);
      }
      int kbase = nxt * 32 + sg * 8;
#pragma unroll
      for (int i = 0; i < 8; ++i) {
        int gk = kbase + i;
        v[i] = (rowok && gk < K1) ? arow[gk] : 0.f;
      }
    }
    // ---- compute tile kb (lane-linear conflict-free ds_reads)
    {
      s16x8 ah[4], al[4];
#pragma unroll
      for (int mt = 0; mt < 4; ++mt) {
        ah[mt] = *(const s16x8*)&As[cur][(mt * 2 + 0) * 512 + l * 8];
        al[mt] = *(const s16x8*)&As[cur][(mt * 2 + 1) * 512 + l * 8];
      }
#pragma unroll
      for (int nt = 0; nt < 4; ++nt) {
        int ng = w * 4 + nt;
        s16x8 bh = *(const s16x8*)&Bs[cur][(ng * 2 + 0) * 512 + l * 8];
        s16x8 bl = *(const s16x8*)&Bs[cur][(ng * 2 + 1) * 512 + l * 8];
#pragma unroll
        for (int mt = 0; mt < 4; ++mt) {
          acc[mt][nt] = __builtin_amdgcn_mfma_f32_16x16x32_bf16(
              ah[mt], bh, acc[mt][nt], 0, 0, 0);
          acc[mt][nt] = __builtin_amdgcn_mfma_f32_16x16x32_bf16(
              ah[mt], bl, acc[mt][nt], 0, 0, 0);
          acc[mt][nt] = __builtin_amdgcn_mfma_f32_16x16x32_bf16(
              al[mt], bh, acc[mt][nt], 0, 0, 0);
        }
      }
    }
    // ---- write next A tile into the other buffer (no barrier needed: disjoint)
    if (nxt < NKB) {
      unsigned short hv[8], lv[8];
#pragma unroll
      for (int e = 0; e < 8; ++e) {
        unsigned short h = f2bf(v[e]);
        hv[e] = h;
        lv[e] = f2bf(v[e] - bf2f(h));
      }
      *(ulonglong2*)&As[cur ^ 1][((smt * 2 + 0) * 64 + lane_dst) * 8] =
          *(ulonglong2*)hv;
      *(ulonglong2*)&As[cur ^ 1][((smt * 2 + 1) * 64 + lane_dst) * 8] =
          *(ulonglong2*)lv;
      __syncthreads();   // drains B(t+1) gll + makes A writes visible
    }
    cur ^= 1;
  }
  // ---- epilogue: tile D layout col = l&15, row = (l>>4)*4 + r
  const int crow4 = (l >> 4) * 4;
  const int ccol = l & 15;
#pragma unroll
  for (int mt = 0; mt < 4; ++mt) {
#pragma unroll
    for (int r = 0; r < 4; ++r) {
      int grow = row0 + mt * 16 + crow4 + r;
      if (grow < M) {
#pragma unroll
        for (int nt = 0; nt < 4; ++nt) {
          int gcol = w * 64 + nt * 16 + ccol;
          C[(long)grow * 256 + gcol] = acc[mt][nt][r];
        }
      }
    }
  }
}

// ---------------- per-node attention logits, layer 1 ----------------
__global__ void alpha1_kernel(const float* __restrict__ h1,
    const float* __restrict__ a_src, const float* __restrict__ a_dst,
    float* __restrict__ as_o, float* __restrict__ ad_o, int N) {
  int i = blockIdx.x * blockDim.x + threadIdx.x;  // i = n*8+h
  if (i >= N * 8) return;
  int h = i & 7;
  const float* hp = h1 + (long)(i >> 3) * 256 + h * 32;
  const float* sp = a_src + h * 32;
  const float* dp = a_dst + h * 32;
  float s1 = 0.f, s2 = 0.f;
#pragma unroll
  for (int c = 0; c < 32; c += 4) {
    float4 v = *(const float4*)(hp + c);
    float4 ws = *(const float4*)(sp + c);
    float4 wd = *(const float4*)(dp + c);
    s1 += v.x * ws.x + v.y * ws.y + v.z * ws.z + v.w * ws.w;
    s2 += v.x * wd.x + v.y * wd.y + v.z * wd.z + v.w * wd.w;
  }
  as_o[i] = s1;
  ad_o[i] = s2;
}

// ================= CSR construction =================
__global__ void hist_kernel(const int* __restrict__ dst, int* __restrict__ cnt,
                            int E, int N) {
  int e = blockIdx.x * blockDim.x + threadIdx.x;
  if (e >= E + N) return;
  int d = (e < E) ? dst[e] : (e - E);
  atomicAdd(&cnt[d], 1);
}

__global__ __launch_bounds__(1024) void scan_kernel(
    const int* __restrict__ cnt, int* __restrict__ rowptr,
    int* __restrict__ cursor, int N) {
  __shared__ int part[1024];
  const int tid = threadIdx.x;
  const int chunk = (N + 1023) / 1024;
  const int base = tid * chunk;
  const int lim = min(base + chunk, N);
  int sum = 0;
  for (int i = base; i < lim; ++i) sum += cnt[i];
  part[tid] = sum;
  __syncthreads();
  for (int off = 1; off < 1024; off <<= 1) {
    int v = (tid >= off) ? part[tid - off] : 0;
    __syncthreads();
    part[tid] += v;
    __syncthreads();
  }
  int run = (tid == 0) ? 0 : part[tid - 1];
  for (int i = base; i < lim; ++i) {
    rowptr[i] = run;
    cursor[i] = run;
    run += cnt[i];
  }
  if (tid == 1023) rowptr[N] = part[1023];
}

__global__ void scatter_kernel(const int* __restrict__ src,
    const int* __restrict__ dst, int* __restrict__ cursor,
    int* __restrict__ csr_src, int E, int N) {
  int e = blockIdx.x * blockDim.x + threadIdx.x;
  if (e >= E + N) return;
  int s, d;
  if (e < E) { s = src[e]; d = dst[e]; } else { s = e - E; d = s; }
  int pos = atomicAdd(&cursor[d], 1);
  csr_src[pos] = s;
}

// ======== layer-1 fused aggregation: wave per dst, no atomics ========
__global__ __launch_bounds__(256) void agg1_fused_kernel(
    const int* __restrict__ rowptr, const int* __restrict__ csr_src,
    const float* __restrict__ as_, const float* __restrict__ ad_,
    const float* __restrict__ h1, const float* __restrict__ bias,
    float* __restrict__ act, int N) {
  int d = blockIdx.x * 4 + (threadIdx.x >> 6);
  if (d >= N) return;
  int l = threadIdx.x & 63;
  int h = l >> 3;
  int rs = rowptr[d], re = rowptr[d + 1];
  float adv = ad_[d * 8 + h];
  float4 acc = make_float4(0.f, 0.f, 0.f, 0.f);
  float den = 0.f;
  for (int i = rs; i < re; ++i) {
    int s = csr_src[i];
    float a = __expf(leaky(as_[s * 8 + h] + adv));
    den += a;
    float4 v = *(const float4*)(h1 + (long)s * 256 + l * 4);
    acc.x += a * v.x; acc.y += a * v.y; acc.z += a * v.z; acc.w += a * v.w;
  }
  float inv = 1.f / den;
  float4 b = *(const float4*)(bias + l * 4);
  float4 o;
  o.x = acc.x * inv + b.x; o.y = acc.y * inv + b.y;
  o.z = acc.z * inv + b.z; o.w = acc.w * inv + b.w;
  o.x = o.x > 0.f ? o.x : expm1f(o.x);
  o.y = o.y > 0.f ? o.y : expm1f(o.y);
  o.z = o.z > 0.f ? o.z : expm1f(o.z);
  o.w = o.w > 0.f ? o.w : expm1f(o.w);
  *(float4*)(act + (long)d * 256 + l * 4) = o;
}

// ---------------- GEMM2 (K=256, N=56) + fused alpha2 ----------------
__global__ __launch_bounds__(256) void gemm2_kernel(const float* __restrict__ act,
    const float* __restrict__ W2, const float* __restrict__ a_src2,
    const float* __restrict__ a_dst2, float* __restrict__ h2,
    float* __restrict__ as_o, float* __restrict__ ad_o, int N) {
  __shared__ float Ws[256 * 56];
  for (int i = threadIdx.x; i < 256 * 56; i += 256) Ws[i] = W2[i];
  __syncthreads();
  int n = blockIdx.x * 32 + (threadIdx.x >> 3);
  int h = threadIdx.x & 7;
  if (n >= N) return;
  const float* ap = act + (long)n * 256;
  float acc[7] = {0.f, 0.f, 0.f, 0.f, 0.f, 0.f, 0.f};
  for (int k0 = 0; k0 < 256; k0 += 4) {
    float4 a = *(const float4*)(ap + k0);
    float av[4] = {a.x, a.y, a.z, a.w};
#pragma unroll
    for (int kk = 0; kk < 4; ++kk) {
      const float* wp = &Ws[(k0 + kk) * 56 + h * 7];
#pragma unroll
      for (int j = 0; j < 7; ++j) acc[j] += av[kk] * wp[j];
    }
  }
  float* hp = h2 + (long)n * 56 + h * 7;
  float s1 = 0.f, s2 = 0.f;
#pragma unroll
  for (int j = 0; j < 7; ++j) {
    hp[j] = acc[j];
    s1 += acc[j] * a_src2[h * 7 + j];
    s2 += acc[j] * a_dst2[h * 7 + j];
  }
  as_o[n * 8 + h] = s1;
  ad_o[n * 8 + h] = s2;
}

// ======== layer-2 fused aggregation: wave per dst ========
__global__ __launch_bounds__(256) void agg2_fused_kernel(
    const int* __restrict__ rowptr, const int* __restrict__ csr_src,
    const float* __restrict__ as_, const float* __restrict__ ad_,
    const float* __restrict__ h2, const float* __restrict__ bias,
    float* __restrict__ out, int N) {
  int d = blockIdx.x * 4 + (threadIdx.x >> 6);
  if (d >= N) return;
  int l = threadIdx.x & 63;
  int h = l >> 3, j = l & 7;
  int rs = rowptr[d], re = rowptr[d + 1];
  float adv = ad_[d * 8 + h];
  float acc = 0.f, den = 0.f;
  for (int i = rs; i < re; ++i) {
    int s = csr_src[i];
    float a = __expf(leaky(as_[s * 8 + h] + adv));
    den += a;
    if (j < 7) acc += a * h2[(long)s * 56 + h * 7 + j];
  }
  if (j < 7) out[(long)d * 56 + h * 7 + j] = acc / den + bias[h * 7 + j];
}

extern "C" void kernel_launch(void* const* d_in, const int* in_sizes, int n_in,
                              void* d_out, int out_size, void* d_ws, size_t ws_size,
                              hipStream_t stream) {
  const float* x    = (const float*)d_in[0];
  const int*   ei   = (const int*)d_in[1];
  const float* W1   = (const float*)d_in[2];
  const float* asr1 = (const float*)d_in[3];
  const float* adt1 = (const float*)d_in[4];
  const float* b1   = (const float*)d_in[5];
  const float* W2   = (const float*)d_in[6];
  const float* asr2 = (const float*)d_in[7];
  const float* adt2 = (const float*)d_in[8];
  const float* b2   = (const float*)d_in[9];
  float* out = (float*)d_out;

  const int N = in_sizes[0] / K1;
  const int E = in_sizes[1] / 2;
  const int* src = ei;
  const int* dst = ei + E;

  float* ws = (float*)d_ws;
  float* h1  = ws; ws += (long)N * 256;
  float* act = ws; ws += (long)N * 256;
  float* h2  = ws; ws += (long)N * 56;
  float* as1 = ws; ws += N * 8;
  float* ad1 = ws; ws += N * 8;
  float* as2 = ws; ws += N * 8;
  float* ad2 = ws; ws += N * 8;
  unsigned short* w1f = (unsigned short*)ws; ws += NKB * 2 * 16 * 64 * 8 / 2;
  int* cnt     = (int*)ws; ws += N;
  int* rowptr  = (int*)ws; ws += N + 1;
  int* cursor  = (int*)ws; ws += N;
  int* csr_src = (int*)ws; ws += E + N;

  hipMemsetAsync(cnt, 0, (size_t)N * sizeof(int), stream);

  dim3 blk(256);

  // CSR build + weight re-layout (cheap)
  hist_kernel<<<dim3((E + N + 255) / 256), blk, 0, stream>>>(dst, cnt, E, N);
  scan_kernel<<<dim3(1), dim3(1024), 0, stream>>>(cnt, rowptr, cursor, N);
  scatter_kernel<<<dim3((E + N + 255) / 256), blk, 0, stream>>>(
      src, dst, cursor, csr_src, E, N);
  {
    int tot = NKB * 2 * 16 * 64;
    w1t_kernel<<<dim3((tot + 255) / 256), blk, 0, stream>>>(W1, w1f);
  }

  gemm1_mfma_kernel<<<dim3((N + 63) / 64), blk, 0, stream>>>(x, w1f, h1, N);
  alpha1_kernel<<<dim3((N * 8 + 255) / 256), blk, 0, stream>>>(h1, asr1, adt1, as1, ad1, N);
  agg1_fused_kernel<<<dim3((N + 3) / 4), blk, 0, stream>>>(
      rowptr, csr_src, as1, ad1, h1, b1, act, N);
  gemm2_kernel<<<dim3((N + 31) / 32), blk, 0, stream>>>(act, W2, asr2, adt2, h2, as2, ad2, N);
  agg2_fused_kernel<<<dim3((N + 3) / 4), blk, 0, stream>>>(
      rowptr, csr_src, as2, ad2, h2, b2, out, N);
}

// Round 7
// 727.098 us; speedup vs baseline: 1.2219x; 1.0214x over previous
//
#include <hip/hip_runtime.h>
#include <math.h>

typedef short s16x8 __attribute__((ext_vector_type(8)));
typedef float f32x4 __attribute__((ext_vector_type(4)));

#define SLOPE 0.2f
#define K1 1433
#define KP 1440   // K padded to multiple of 32
#define NKB 45    // KP/32

static __device__ __forceinline__ float leaky(float x) {
  return x > 0.f ? x : SLOPE * x;
}

static __device__ __forceinline__ unsigned short f2bf(float f) {
  unsigned u = __builtin_bit_cast(unsigned, f);
  u += 0x7FFFu + ((u >> 16) & 1u);
  return (unsigned short)(u >> 16);
}
static __device__ __forceinline__ float bf2f(unsigned short h) {
  unsigned u = ((unsigned)h) << 16;
  return __builtin_bit_cast(float, u);
}

// --------- W1 -> fragment-order bf16(hi) table ---------
// chunk index = kb*16 + ntg; value = W1[k][n], n = ntg*16 + (l&15),
// k = kb*32 + (l>>4)*8 + e (0 pad k>=K1)
__global__ void w1t_kernel(const float* __restrict__ W1,
                           unsigned short* __restrict__ w1f) {
  int tid = blockIdx.x * 256 + threadIdx.x;       // one thread = one 16B chunk
  if (tid >= NKB * 16 * 64) return;
  int l = tid & 63;
  int chunk = tid >> 6;                            // kb*16 + ntg
  int ntg = chunk & 15;
  int kb = chunk >> 4;
  int n = ntg * 16 + (l & 15);
  int kbase = kb * 32 + (l >> 4) * 8;
  unsigned short o[8];
#pragma unroll
  for (int e = 0; e < 8; ++e) {
    int k = kbase + e;
    float v = (k < K1) ? W1[(long)k * 256 + n] : 0.f;
    o[e] = f2bf(v);
  }
  *(ulonglong2*)(w1f + (long)tid * 8) = *(ulonglong2*)o;
}

// --------- GEMM1: 2-term split A(hi,lo) x B(hi), pipelined ---------
// block: 256 thr = 4 waves of 64x64 wave tiles (BM=64, BN=256, BK=32).
// LDS: As 2x8KB + Bs 2x16KB = 48KB -> 3 blocks/CU.
__global__ __launch_bounds__(256, 3) void gemm1_mfma_kernel(
    const float* __restrict__ A, const unsigned short* __restrict__ w1f,
    float* __restrict__ C, int M) {
  __shared__ unsigned short As[2][4 * 2 * 64 * 8];    // 2 x 8 KB
  __shared__ unsigned short Bs[2][16 * 64 * 8];       // 2 x 16 KB
  const int t = threadIdx.x;
  const int w = t >> 6, l = t & 63;
  const int row0 = blockIdx.x * 64;

  f32x4 acc[4][4];
#pragma unroll
  for (int mt = 0; mt < 4; ++mt)
#pragma unroll
    for (int nt = 0; nt < 4; ++nt)
#pragma unroll
      for (int r = 0; r < 4; ++r) acc[mt][nt][r] = 0.f;

  // A staging geometry: row sr = t>>2 (0..63), k-group sg = t&3 (8 k each)
  const int sr = t >> 2, sg = t & 3;
  const int smt = sr >> 4, slr = sr & 15;
  const int lane_dst = slr + 16 * sg;           // fragment lane index
  const bool rowok = (row0 + sr) < M;
  const float* arow = A + (long)(row0 + sr) * K1;

  float v[8];

  // prologue: stage tile 0
#pragma unroll
  for (int q = 0; q < 4; ++q) {
    int ng = w * 4 + q;
    const unsigned short* gsrc = w1f + (((long)0 * 16 + ng) * 64 + l) * 8;
    unsigned short* ldst = &Bs[0][ng * 512];
    __builtin_amdgcn_global_load_lds(
        (const __attribute__((address_space(1))) unsigned int*)gsrc,
        (__attribute__((address_space(3))) unsigned int*)ldst, 16, 0, 0);
  }
  {
    int kbase = sg * 8;
#pragma unroll
    for (int i = 0; i < 8; ++i) {
      int gk = kbase + i;
      v[i] = (rowok && gk < K1) ? arow[gk] : 0.f;
    }
    unsigned short hv[8], lv[8];
#pragma unroll
    for (int e = 0; e < 8; ++e) {
      unsigned short h = f2bf(v[e]);
      hv[e] = h;
      lv[e] = f2bf(v[e] - bf2f(h));
    }
    *(ulonglong2*)&As[0][((smt * 2 + 0) * 64 + lane_dst) * 8] = *(ulonglong2*)hv;
    *(ulonglong2*)&As[0][((smt * 2 + 1) * 64 + lane_dst) * 8] = *(ulonglong2*)lv;
  }
  __syncthreads();

  int cur = 0;
  for (int kb = 0; kb < NKB; ++kb) {
    const int nxt = kb + 1;
    // ---- issue next tile's loads (hide under MFMA below)
    if (nxt < NKB) {
#pragma unroll
      for (int q = 0; q < 4; ++q) {
        int ng = w * 4 + q;
        const unsigned short* gsrc =
            w1f + (((long)nxt * 16 + ng) * 64 + l) * 8;
        unsigned short* ldst = &Bs[cur ^ 1][ng * 512];
        __builtin_amdgcn_global_load_lds(
            (const __attribute__((address_space(1))) unsigned int*)gsrc,
            (__attribute__((address_space(3))) unsigned int*)ldst, 16, 0, 0);
      }
      int kbase = nxt * 32 + sg * 8;
#pragma unroll
      for (int i = 0; i < 8; ++i) {
        int gk = kbase + i;
        v[i] = (rowok && gk < K1) ? arow[gk] : 0.f;
      }
    }
    // ---- compute tile kb: 12 lane-linear ds_reads + 32 MFMA
    {
      s16x8 ah[4], al[4], bh[4];
#pragma unroll
      for (int mt = 0; mt < 4; ++mt) {
        ah[mt] = *(const s16x8*)&As[cur][(mt * 2 + 0) * 512 + l * 8];
        al[mt] = *(const s16x8*)&As[cur][(mt * 2 + 1) * 512 + l * 8];
      }
#pragma unroll
      for (int nt = 0; nt < 4; ++nt)
        bh[nt] = *(const s16x8*)&Bs[cur][(w * 4 + nt) * 512 + l * 8];
#pragma unroll
      for (int nt = 0; nt < 4; ++nt)
#pragma unroll
        for (int mt = 0; mt < 4; ++mt) {
          acc[mt][nt] = __builtin_amdgcn_mfma_f32_16x16x32_bf16(
              ah[mt], bh[nt], acc[mt][nt], 0, 0, 0);
          acc[mt][nt] = __builtin_amdgcn_mfma_f32_16x16x32_bf16(
              al[mt], bh[nt], acc[mt][nt], 0, 0, 0);
        }
    }
    // ---- write next A tile into other buffer, then single barrier
    if (nxt < NKB) {
      unsigned short hv[8], lv[8];
#pragma unroll
      for (int e = 0; e < 8; ++e) {
        unsigned short h = f2bf(v[e]);
        hv[e] = h;
        lv[e] = f2bf(v[e] - bf2f(h));
      }
      *(ulonglong2*)&As[cur ^ 1][((smt * 2 + 0) * 64 + lane_dst) * 8] =
          *(ulonglong2*)hv;
      *(ulonglong2*)&As[cur ^ 1][((smt * 2 + 1) * 64 + lane_dst) * 8] =
          *(ulonglong2*)lv;
      __syncthreads();   // drains B(t+1) gll + makes A writes visible
    }
    cur ^= 1;
  }
  // ---- epilogue: tile D layout col = l&15, row = (l>>4)*4 + r
  const int crow4 = (l >> 4) * 4;
  const int ccol = l & 15;
#pragma unroll
  for (int mt = 0; mt < 4; ++mt) {
#pragma unroll
    for (int r = 0; r < 4; ++r) {
      int grow = row0 + mt * 16 + crow4 + r;
      if (grow < M) {
#pragma unroll
        for (int nt = 0; nt < 4; ++nt) {
          int gcol = w * 64 + nt * 16 + ccol;
          C[(long)grow * 256 + gcol] = acc[mt][nt][r];
        }
      }
    }
  }
}

// ------- attention logits, layer 1 + emit bf16 copy of h1 -------
__global__ void alpha1_kernel(const float* __restrict__ h1,
    const float* __restrict__ a_src, const float* __restrict__ a_dst,
    float* __restrict__ as_o, float* __restrict__ ad_o,
    unsigned short* __restrict__ h1b, int N) {
  int i = blockIdx.x * blockDim.x + threadIdx.x;  // i = n*8+h
  if (i >= N * 8) return;
  int h = i & 7;
  const float* hp = h1 + (long)(i >> 3) * 256 + h * 32;
  const float* sp = a_src + h * 32;
  const float* dp = a_dst + h * 32;
  unsigned short ob[32];
  float s1 = 0.f, s2 = 0.f;
#pragma unroll
  for (int c = 0; c < 32; c += 4) {
    float4 v = *(const float4*)(hp + c);
    float4 ws = *(const float4*)(sp + c);
    float4 wd = *(const float4*)(dp + c);
    s1 += v.x * ws.x + v.y * ws.y + v.z * ws.z + v.w * ws.w;
    s2 += v.x * wd.x + v.y * wd.y + v.z * wd.z + v.w * wd.w;
    ob[c] = f2bf(v.x); ob[c + 1] = f2bf(v.y);
    ob[c + 2] = f2bf(v.z); ob[c + 3] = f2bf(v.w);
  }
  as_o[i] = s1;
  ad_o[i] = s2;
  unsigned short* op = h1b + (long)(i >> 3) * 256 + h * 32;
#pragma unroll
  for (int c = 0; c < 32; c += 8)
    *(ulonglong2*)(op + c) = *(ulonglong2*)(ob + c);
}

// ================= CSR construction =================
__global__ void hist_kernel(const int* __restrict__ dst, int* __restrict__ cnt,
                            int E, int N) {
  int e = blockIdx.x * blockDim.x + threadIdx.x;
  if (e >= E + N) return;
  int d = (e < E) ? dst[e] : (e - E);
  atomicAdd(&cnt[d], 1);
}

__global__ __launch_bounds__(1024) void scan_kernel(
    const int* __restrict__ cnt, int* __restrict__ rowptr,
    int* __restrict__ cursor, int N) {
  __shared__ int part[1024];
  const int tid = threadIdx.x;
  const int chunk = (N + 1023) / 1024;
  const int base = tid * chunk;
  const int lim = min(base + chunk, N);
  int sum = 0;
  for (int i = base; i < lim; ++i) sum += cnt[i];
  part[tid] = sum;
  __syncthreads();
  for (int off = 1; off < 1024; off <<= 1) {
    int v = (tid >= off) ? part[tid - off] : 0;
    __syncthreads();
    part[tid] += v;
    __syncthreads();
  }
  int run = (tid == 0) ? 0 : part[tid - 1];
  for (int i = base; i < lim; ++i) {
    rowptr[i] = run;
    cursor[i] = run;
    run += cnt[i];
  }
  if (tid == 1023) rowptr[N] = part[1023];
}

__global__ void scatter_kernel(const int* __restrict__ src,
    const int* __restrict__ dst, int* __restrict__ cursor,
    int* __restrict__ csr_src, int E, int N) {
  int e = blockIdx.x * blockDim.x + threadIdx.x;
  if (e >= E + N) return;
  int s, d;
  if (e < E) { s = src[e]; d = dst[e]; } else { s = e - E; d = s; }
  int pos = atomicAdd(&cursor[d], 1);
  csr_src[pos] = s;
}

// ======== layer-1 fused aggregation: wave per dst, bf16 gather ========
__global__ __launch_bounds__(256) void agg1_fused_kernel(
    const int* __restrict__ rowptr, const int* __restrict__ csr_src,
    const float* __restrict__ as_, const float* __restrict__ ad_,
    const unsigned short* __restrict__ h1b, const float* __restrict__ bias,
    float* __restrict__ act, int N) {
  int d = blockIdx.x * 4 + (threadIdx.x >> 6);
  if (d >= N) return;
  int l = threadIdx.x & 63;
  int h = l >> 3;
  int rs = rowptr[d], re = rowptr[d + 1];
  float adv = ad_[d * 8 + h];
  float4 acc = make_float4(0.f, 0.f, 0.f, 0.f);
  float den = 0.f;
  for (int i = rs; i < re; ++i) {
    int s = csr_src[i];
    float a = __expf(leaky(as_[s * 8 + h] + adv));
    den += a;
    ushort4 u = *(const ushort4*)(h1b + (long)s * 256 + l * 4);
    acc.x += a * bf2f(u.x); acc.y += a * bf2f(u.y);
    acc.z += a * bf2f(u.z); acc.w += a * bf2f(u.w);
  }
  float inv = 1.f / den;
  float4 b = *(const float4*)(bias + l * 4);
  float4 o;
  o.x = acc.x * inv + b.x; o.y = acc.y * inv + b.y;
  o.z = acc.z * inv + b.z; o.w = acc.w * inv + b.w;
  o.x = o.x > 0.f ? o.x : expm1f(o.x);
  o.y = o.y > 0.f ? o.y : expm1f(o.y);
  o.z = o.z > 0.f ? o.z : expm1f(o.z);
  o.w = o.w > 0.f ? o.w : expm1f(o.w);
  *(float4*)(act + (long)d * 256 + l * 4) = o;
}

// ---------------- GEMM2 (K=256, N=56) + fused alpha2, bf16 h2 ----------------
__global__ __launch_bounds__(256) void gemm2_kernel(const float* __restrict__ act,
    const float* __restrict__ W2, const float* __restrict__ a_src2,
    const float* __restrict__ a_dst2, unsigned short* __restrict__ h2b,
    float* __restrict__ as_o, float* __restrict__ ad_o, int N) {
  __shared__ float Ws[256 * 56];
  for (int i = threadIdx.x; i < 256 * 56; i += 256) Ws[i] = W2[i];
  __syncthreads();
  int n = blockIdx.x * 32 + (threadIdx.x >> 3);
  int h = threadIdx.x & 7;
  if (n >= N) return;
  const float* ap = act + (long)n * 256;
  float acc[7] = {0.f, 0.f, 0.f, 0.f, 0.f, 0.f, 0.f};
  for (int k0 = 0; k0 < 256; k0 += 4) {
    float4 a = *(const float4*)(ap + k0);
    float av[4] = {a.x, a.y, a.z, a.w};
#pragma unroll
    for (int kk = 0; kk < 4; ++kk) {
      const float* wp = &Ws[(k0 + kk) * 56 + h * 7];
#pragma unroll
      for (int j = 0; j < 7; ++j) acc[j] += av[kk] * wp[j];
    }
  }
  unsigned short* hp = h2b + (long)n * 56 + h * 7;
  float s1 = 0.f, s2 = 0.f;
#pragma unroll
  for (int j = 0; j < 7; ++j) {
    hp[j] = f2bf(acc[j]);
    s1 += acc[j] * a_src2[h * 7 + j];
    s2 += acc[j] * a_dst2[h * 7 + j];
  }
  as_o[n * 8 + h] = s1;
  ad_o[n * 8 + h] = s2;
}

// ======== layer-2 fused aggregation: wave per dst, bf16 gather ========
__global__ __launch_bounds__(256) void agg2_fused_kernel(
    const int* __restrict__ rowptr, const int* __restrict__ csr_src,
    const float* __restrict__ as_, const float* __restrict__ ad_,
    const unsigned short* __restrict__ h2b, const float* __restrict__ bias,
    float* __restrict__ out, int N) {
  int d = blockIdx.x * 4 + (threadIdx.x >> 6);
  if (d >= N) return;
  int l = threadIdx.x & 63;
  int h = l >> 3, j = l & 7;
  int rs = rowptr[d], re = rowptr[d + 1];
  float adv = ad_[d * 8 + h];
  float acc = 0.f, den = 0.f;
  for (int i = rs; i < re; ++i) {
    int s = csr_src[i];
    float a = __expf(leaky(as_[s * 8 + h] + adv));
    den += a;
    if (j < 7) acc += a * bf2f(h2b[(long)s * 56 + h * 7 + j]);
  }
  if (j < 7) out[(long)d * 56 + h * 7 + j] = acc / den + bias[h * 7 + j];
}

extern "C" void kernel_launch(void* const* d_in, const int* in_sizes, int n_in,
                              void* d_out, int out_size, void* d_ws, size_t ws_size,
                              hipStream_t stream) {
  const float* x    = (const float*)d_in[0];
  const int*   ei   = (const int*)d_in[1];
  const float* W1   = (const float*)d_in[2];
  const float* asr1 = (const float*)d_in[3];
  const float* adt1 = (const float*)d_in[4];
  const float* b1   = (const float*)d_in[5];
  const float* W2   = (const float*)d_in[6];
  const float* asr2 = (const float*)d_in[7];
  const float* adt2 = (const float*)d_in[8];
  const float* b2   = (const float*)d_in[9];
  float* out = (float*)d_out;

  const int N = in_sizes[0] / K1;
  const int E = in_sizes[1] / 2;
  const int* src = ei;
  const int* dst = ei + E;

  float* ws = (float*)d_ws;
  float* h1  = ws; ws += (long)N * 256;
  float* act = ws; ws += (long)N * 256;
  float* as1 = ws; ws += N * 8;
  float* ad1 = ws; ws += N * 8;
  float* as2 = ws; ws += N * 8;
  float* ad2 = ws; ws += N * 8;
  unsigned short* h1b = (unsigned short*)ws; ws += (long)N * 128;  // N*256 bf16
  unsigned short* h2b = (unsigned short*)ws; ws += (long)N * 28;   // N*56 bf16
  unsigned short* w1f = (unsigned short*)ws; ws += NKB * 16 * 64 * 8 / 2;
  int* cnt     = (int*)ws; ws += N;
  int* rowptr  = (int*)ws; ws += N + 1;
  int* cursor  = (int*)ws; ws += N;
  int* csr_src = (int*)ws; ws += E + N;

  hipMemsetAsync(cnt, 0, (size_t)N * sizeof(int), stream);

  dim3 blk(256);

  // CSR build + weight re-layout (cheap)
  hist_kernel<<<dim3((E + N + 255) / 256), blk, 0, stream>>>(dst, cnt, E, N);
  scan_kernel<<<dim3(1), dim3(1024), 0, stream>>>(cnt, rowptr, cursor, N);
  scatter_kernel<<<dim3((E + N + 255) / 256), blk, 0, stream>>>(
      src, dst, cursor, csr_src, E, N);
  {
    int tot = NKB * 16 * 64;
    w1t_kernel<<<dim3((tot + 255) / 256), blk, 0, stream>>>(W1, w1f);
  }

  gemm1_mfma_kernel<<<dim3((N + 63) / 64), blk, 0, stream>>>(x, w1f, h1, N);
  alpha1_kernel<<<dim3((N * 8 + 255) / 256), blk, 0, stream>>>(
      h1, asr1, adt1, as1, ad1, h1b, N);
  agg1_fused_kernel<<<dim3((N + 3) / 4), blk, 0, stream>>>(
      rowptr, csr_src, as1, ad1, h1b, b1, act, N);
  gemm2_kernel<<<dim3((N + 31) / 32), blk, 0, stream>>>(
      act, W2, asr2, adt2, h2b, as2, ad2, N);
  agg2_fused_kernel<<<dim3((N + 3) / 4), blk, 0, stream>>>(
      rowptr, csr_src, as2, ad2, h2b, b2, out, N);
}